// Round 8
// baseline (25220.204 us; speedup 1.0000x reference)
//
#include <hip/hip_runtime.h>
#include <math.h>

#define Bsz 16
#define Lsz 400
#define Tsz 200
#define NMELS 80
#define ENC 512
#define PREsz 256
#define QHsz 1024
#define DHsz 1024
#define ATTNsz 128
#define NFILT 32
#define KW 31
#define PADW 15
#define NB 256

typedef const float* __restrict__ cfp;
typedef float* __restrict__ fp;
typedef __fp16 hf;
typedef __fp16 h2 __attribute__((ext_vector_type(2)));
typedef const hf* __restrict__ chp;

union F4H { float4 f; h2 h[4]; };

__device__ __forceinline__ float4 ldf4(const float* p){ return *reinterpret_cast<const float4*>(p); }
__device__ __forceinline__ float sigm(float x){ return 1.0f/(1.0f + __expf(-x)); }
__device__ __forceinline__ float tanhfast(float x){
  x = fminf(fmaxf(x, -15.0f), 15.0f);
  float e = __expf(2.0f*x);
  return (e-1.0f)/(e+1.0f);
}
__device__ __forceinline__ h2 pk2(float a, float b){
  return __builtin_amdgcn_cvt_pkrtz(a, b);
}
__device__ __forceinline__ float fdot2f(h2 a, h2 b, float c){
#if __has_builtin(__builtin_amdgcn_fdot2)
  return __builtin_amdgcn_fdot2(a, b, c, false);
#else
  return c + (float)a.x*(float)b.x + (float)a.y*(float)b.y;
#endif
}

// device-scope grid barrier: monotonic counter, all NB blocks arrive.
__device__ __forceinline__ void gridbar(int* cnt, int target){
  __syncthreads();            // drains vmcnt -> block stores in L2
  if (threadIdx.x == 0){
    __threadfence();          // L2 writeback (agent release)
    __hip_atomic_fetch_add(cnt, 1, __ATOMIC_RELAXED, __HIP_MEMORY_SCOPE_AGENT);
    while (__hip_atomic_load(cnt, __ATOMIC_RELAXED, __HIP_MEMORY_SCOPE_AGENT) < target)
      __builtin_amdgcn_s_sleep(1);
    __threadfence();          // invalidate stale L1/L2 (agent acquire)
  }
  __syncthreads();
}

__global__ void kzero(fp p, int n){
  int i = blockIdx.x*256 + threadIdx.x;
  if (i < n) p[i] = 0.0f;
}

__global__ void kcvt(cfp src, hf* __restrict__ dst, int n){
  int i = (blockIdx.x*256 + threadIdx.x)*4;
  if (i + 3 < n){
    float4 v = ldf4(src + i);
    dst[i+0] = (hf)v.x; dst[i+1] = (hf)v.y; dst[i+2] = (hf)v.z; dst[i+3] = (hf)v.w;
  } else {
    for (int k=i; k<n; k++) dst[k] = (hf)src[k];
  }
}

// prenet (one-time): 208 blocks
__global__ void __launch_bounds__(256) kprenet2(cfp teacher, cfp w1, cfp w2, fp dec_ins){
  int b = blockIdx.x & 15, tc = blockIdx.x >> 4;
  int t0 = tc*16;
  int tid = threadIdx.x;
  __shared__ __align__(16) float tch[16][80];
  __shared__ __align__(16) float h1[16][256];
  for (int idx = tid; idx < 16*80; idx += 256){
    int i = idx / 80, k = idx % 80;
    int t = t0 + i;
    float v = 0.f;
    if (t >= 1 && t < Tsz) v = teacher[((size_t)b*Tsz + (t-1))*NMELS + k];
    tch[i][k] = v;
  }
  __syncthreads();
  {
    int r = tid;
    float acc[16];
    #pragma unroll
    for (int i=0;i<16;i++) acc[i]=0.f;
    const float* wr = w1 + (size_t)r*80;
    for (int k=0;k<80;k++){
      float w = wr[k];
      #pragma unroll
      for (int i=0;i<16;i++) acc[i] += w * tch[i][k];
    }
    #pragma unroll
    for (int i=0;i<16;i++) h1[i][r] = fmaxf(acc[i], 0.f);
  }
  __syncthreads();
  {
    int r = tid;
    float acc[16];
    #pragma unroll
    for (int i=0;i<16;i++) acc[i]=0.f;
    const float* wr = w2 + (size_t)r*256;
    for (int k=0;k<256;k++){
      float w = wr[k];
      #pragma unroll
      for (int i=0;i<16;i++) acc[i] += w * h1[i][k];
    }
    for (int i=0;i<16;i++){
      int t = t0 + i;
      if (t < Tsz){
        float v = (t == 0) ? 0.f : fmaxf(acc[i], 0.f);
        dec_ins[((size_t)t*Bsz + b)*PREsz + r] = v;
      }
    }
  }
}

// pm (one-time, fp16 output): 400 blocks
__global__ void __launch_bounds__(256) kpm2h(cfp memory, cfp wm, hf* __restrict__ pmh){
  int b = blockIdx.x / 25, lc = blockIdx.x % 25;
  int l0 = lc*16;
  int tid = threadIdx.x;
  __shared__ __align__(16) float mrow[16][512];
  {
    const float4* s4 = (const float4*)(memory + ((size_t)b*Lsz + l0)*ENC);
    float4* d4 = (float4*)&mrow[0][0];
    #pragma unroll
    for (int i=0;i<8;i++) d4[tid + i*256] = s4[tid + i*256];
  }
  __syncthreads();
  int a = tid & 127, g = tid >> 7;
  const float* wr = wm + (size_t)a*ENC;
  float acc[8];
  #pragma unroll
  for (int i=0;i<8;i++) acc[i]=0.f;
  for (int k=0;k<512;k+=4){
    float4 w4 = ldf4(wr + k);
    #pragma unroll
    for (int i=0;i<8;i++){
      float4 x4 = ldf4(&mrow[g*8+i][k]);
      acc[i] += w4.x*x4.x + w4.y*x4.y + w4.z*x4.z + w4.w*x4.w;
    }
  }
  #pragma unroll
  for (int i=0;i<8;i++)
    pmh[((size_t)b*Lsz + l0 + g*8 + i)*ATTNsz + a] = (hf)acc[i];
}

struct GateSmem { __align__(16) h2 xsh[16][132]; };
struct ConvSmem { float hists[2][80]; float convo[NFILT][50]; float cwsh[NFILT*2*KW]; float stat2[2]; };
struct M1Q { __align__(16) float zsh[4096]; __align__(16) h2 qh2l[512]; };
struct M1D { __align__(16) float zsh[4096]; __align__(16) h2 feath[768]; float scs[4]; };
struct M2S { float pqv[128]; float vsh[128]; float esh[100]; float pesh[100]; float red[256]; __align__(16) float4 psum[128]; };
union SMemAll { GateSmem g; ConvSmem c; M1Q mq; M1D md; M2S m2; };

// ---------------- persistent kernel: all 201 macro-steps ----------------
__global__ void __launch_bounds__(256) kpers(
    cfp dec_ins, chp pmh, hf* __restrict__ loch, cfp memory,
    fp qpart, fp dpart, fp pqws,
    fp ebuf2, fp emax2, fp esum2, fp cpart2,
    fp qh_state, fp dh_state, fp qc2, fp dc2, fp aws2,
    int* cnt,
    chp h_qwih, chp h_qwhh, chp h_dwih, chp h_dwhh,
    chp h_wq, chp h_proj, chp h_gate,
    cfp q_bih, cfp q_bhh, cfp d_bih, cfp d_bhh,
    cfp conv_w, cfp wloc, cfp vvec, cfp proj_b, cfp gate_b,
    fp out_mel, fp out_align, fp out_stop)
{
  int bid = blockIdx.x, tid = threadIdx.x;
  __shared__ SMemAll sm;
  int bt = 0;

  for (int t = 0; t <= Tsz; t++){
    int pp = (t+1)&1, qq = t&1;
    int do_q = (t < Tsz), do_d = (t > 0);
    cfp cpartP = cpart2 + pp*32768;
    cfp emaxP = emax2 + pp*64;  cfp esumP = esum2 + pp*64;  cfp ebufP = ebuf2 + pp*6400;
    fp  cpartQ = cpart2 + qq*32768;
    fp  emaxQ = emax2 + qq*64;  fp  esumQ = esum2 + qq*64;  fp  ebufQ = ebuf2 + qq*6400;
    cfp awsP = aws2 + pp*6400;  fp  awsQ = aws2 + qq*6400;
    cfp qcP = qc2 + pp*16384;   fp  qcQ = qc2 + qq*16384;
    cfp dcP = dc2 + pp*16384;   fp  dcQ = dc2 + qq*16384;

    // ======== Phase G: gate partials + conv + updater ========
    for (int u = bid; u < 2320; u += NB){
      if (u < 2176){
        int isq = (u < 896);
        if (isq ? !do_q : !do_d) continue;
        int idx = isq ? u : (u - 896);
        int nch = isq ? 7 : 10;
        int c = idx % nch, rg = idx / nch;
        int bb = tid >> 4, quar = tid & 15;
        int is_ctx = isq ? (c >= 1 && c <= 2) : (c <= 1);
        int ctxoff = isq ? (c-1)*256 : c*256;
        h2* dst = &sm.g.xsh[bb][quar*8];
        if (is_ctx){
          if (!do_d){
            h2 z = pk2(0.f, 0.f);
            #pragma unroll
            for (int i=0;i<8;i++) dst[i] = z;
          } else {
            float m0=emaxP[bb*4+0], m1=emaxP[bb*4+1], m2=emaxP[bb*4+2], m3=emaxP[bb*4+3];
            float gm = fmaxf(fmaxf(m0,m1), fmaxf(m2,m3));
            float e0=__expf(m0-gm), e1=__expf(m1-gm), e2=__expf(m2-gm), e3=__expf(m3-gm);
            float gs = esumP[bb*4+0]*e0 + esumP[bb*4+1]*e1 + esumP[bb*4+2]*e2 + esumP[bb*4+3]*e3;
            float inv = 1.0f/gs;
            float s0=e0*inv, s1=e1*inv, s2=e2*inv, s3=e3*inv;
            const float* cp = cpartP + (size_t)bb*2048 + ctxoff + quar*16;
            #pragma unroll
            for (int kk=0;kk<16;kk+=4){
              float4 p0 = ldf4(cp+kk), p1 = ldf4(cp+512+kk), p2 = ldf4(cp+1024+kk), p3 = ldf4(cp+1536+kk);
              float ax = s0*p0.x + s1*p1.x + s2*p2.x + s3*p3.x;
              float ay = s0*p0.y + s1*p1.y + s2*p2.y + s3*p3.y;
              float az = s0*p0.z + s1*p1.z + s2*p2.z + s3*p3.z;
              float aw = s0*p0.w + s1*p1.w + s2*p2.w + s3*p3.w;
              dst[(kk>>1)+0] = pk2(ax, ay);
              dst[(kk>>1)+1] = pk2(az, aw);
            }
          }
        } else {
          const float* src;
          if (isq){
            if (c == 0)      src = dec_ins + (size_t)t*Bsz*PREsz + bb*PREsz;
            else             src = qh_state + bb*QHsz + (c-3)*256;
          } else {
            if (c < 6)       src = qh_state + bb*QHsz + (c-2)*256;
            else             src = dh_state + bb*DHsz + (c-6)*256;
          }
          const float4* s4 = (const float4*)(src + quar*16);
          float4 t0=s4[0], t1=s4[1], t2=s4[2], t3=s4[3];
          dst[0]=pk2(t0.x,t0.y); dst[1]=pk2(t0.z,t0.w);
          dst[2]=pk2(t1.x,t1.y); dst[3]=pk2(t1.z,t1.w);
          dst[4]=pk2(t2.x,t2.y); dst[5]=pk2(t2.z,t2.w);
          dst[6]=pk2(t3.x,t3.y); dst[7]=pk2(t3.z,t3.w);
        }
        __syncthreads();
        int b = tid & 15, rl = tid >> 4;
        int row0 = rg*32 + rl*2;
        const hf* wbase; int wstride, woff;
        if (isq){
          if (c < 3){ wbase = h_qwih; wstride = 768;  woff = c*256; }
          else      { wbase = h_qwhh; wstride = 1024; woff = (c-3)*256; }
        } else {
          if (c < 6){ wbase = h_dwih; wstride = 1536; woff = c*256; }
          else      { wbase = h_dwhh; wstride = 1024; woff = (c-6)*256; }
        }
        const h2* w0 = (const h2*)(wbase + (size_t)row0*wstride + woff);
        const h2* w1 = (const h2*)(wbase + (size_t)(row0+1)*wstride + woff);
        const h2* xr = &sm.g.xsh[b][0];
        float a0=0.f, a1=0.f;
        #pragma unroll 4
        for (int kb=0; kb<128; kb+=8){
          F4H u0, u1, u2, u3, xA, xB;
          u0.f = ldf4((const float*)(w0 + kb));
          u1.f = ldf4((const float*)(w0 + kb + 4));
          u2.f = ldf4((const float*)(w1 + kb));
          u3.f = ldf4((const float*)(w1 + kb + 4));
          xA.f = ldf4((const float*)(xr + kb));
          xB.f = ldf4((const float*)(xr + kb + 4));
          #pragma unroll
          for (int j=0;j<4;j++){
            a0 = fdot2f(u0.h[j], xA.h[j], a0);
            a0 = fdot2f(u1.h[j], xB.h[j], a0);
            a1 = fdot2f(u2.h[j], xA.h[j], a1);
            a1 = fdot2f(u3.h[j], xB.h[j], a1);
          }
        }
        float2 out = {a0, a1};
        fp part = isq ? qpart : dpart;
        *reinterpret_cast<float2*>(part + ((size_t)(c*16 + b))*4096 + row0) = out;
        __syncthreads();
      } else if (u < 2304){
        if (!do_q) continue;
        int cb = u - 2176;
        int b = cb >> 3, chunk = cb & 7;
        int l0 = chunk*50;
        for (int i=tid; i<NFILT*2*KW; i+=256) sm.c.cwsh[i] = conv_w[i];
        if (tid == 0 && do_d){
          float m0=emaxP[b*4+0], m1=emaxP[b*4+1], m2=emaxP[b*4+2], m3=emaxP[b*4+3];
          float gm = fmaxf(fmaxf(m0,m1), fmaxf(m2,m3));
          float gs = esumP[b*4+0]*__expf(m0-gm) + esumP[b*4+1]*__expf(m1-gm)
                   + esumP[b*4+2]*__expf(m2-gm) + esumP[b*4+3]*__expf(m3-gm);
          sm.c.stat2[0] = gm; sm.c.stat2[1] = 1.0f/gs;
        }
        __syncthreads();
        float gm = sm.c.stat2[0], ginv = sm.c.stat2[1];
        for (int i=tid; i<80; i+=256){
          int pos = l0 - PADW + i;
          float w = 0.f, as = 0.f;
          if (do_d && pos >= 0 && pos < Lsz){
            w = __expf(ebufP[b*Lsz + pos] - gm) * ginv;
            as = awsP[b*Lsz + pos] + w;
          }
          sm.c.hists[0][i] = w;
          sm.c.hists[1][i] = as;
        }
        __syncthreads();
        for (int task=tid; task<NFILT*50; task+=256){
          int f = task & 31, ll = task >> 5;
          float a = 0.0f;
          const float* c0 = &sm.c.cwsh[(f*2+0)*KW];
          const float* c1 = &sm.c.cwsh[(f*2+1)*KW];
          #pragma unroll
          for (int k=0;k<KW;k++) a += sm.c.hists[0][ll+k]*c0[k] + sm.c.hists[1][ll+k]*c1[k];
          sm.c.convo[f][ll] = a;
        }
        __syncthreads();
        for (int task=tid; task<50*ATTNsz; task+=256){
          int a = task & 127, ll = task >> 7;
          float s = 0.0f;
          const float* wl = wloc + a*NFILT;
          #pragma unroll
          for (int f=0;f<NFILT;f++) s += sm.c.convo[f][ll]*wl[f];
          loch[((size_t)b*Lsz + l0 + ll)*ATTNsz + a] = (hf)s;
        }
        __syncthreads();
      } else {
        if (!do_d) continue;
        int b = u - 2304;
        if (tid == 0){
          float m0=emaxP[b*4+0], m1=emaxP[b*4+1], m2=emaxP[b*4+2], m3=emaxP[b*4+3];
          float gm = fmaxf(fmaxf(m0,m1), fmaxf(m2,m3));
          float gs = esumP[b*4+0]*__expf(m0-gm) + esumP[b*4+1]*__expf(m1-gm)
                   + esumP[b*4+2]*__expf(m2-gm) + esumP[b*4+3]*__expf(m3-gm);
          sm.c.stat2[0] = gm; sm.c.stat2[1] = 1.0f/gs;
        }
        __syncthreads();
        float gm = sm.c.stat2[0], ginv = sm.c.stat2[1];
        for (int l=tid; l<Lsz; l+=256){
          float w = __expf(ebufP[b*Lsz + l] - gm) * ginv;
          awsQ[b*Lsz + l] = awsP[b*Lsz + l] + w;
          out_align[((size_t)b*Tsz + (t-1))*Lsz + l] = w;
        }
        __syncthreads();
      }
    }
    bt++; gridbar(cnt, bt*NB);

    // ======== Phase M1: q-cell + pq (16 blocks) ; d-cell + mel (32 blocks) ========
    if (bid < 16){
      if (do_q){
        int b = bid;
        #pragma unroll
        for (int i=0;i<4;i++){
          int r4 = (tid + i*256)*4;
          float4 bi = ldf4(q_bih + r4), bh = ldf4(q_bhh + r4);
          float4 a = {bi.x+bh.x, bi.y+bh.y, bi.z+bh.z, bi.w+bh.w};
          #pragma unroll
          for (int c=0;c<7;c++){
            float4 p = ldf4(qpart + ((size_t)(c*16 + b))*4096 + r4);
            a.x += p.x; a.y += p.y; a.z += p.z; a.w += p.w;
          }
          *reinterpret_cast<float4*>(&sm.mq.zsh[r4]) = a;
        }
        __syncthreads();
        {
          int j4 = tid*4;
          float4 zi = ldf4(&sm.mq.zsh[j4]), zf = ldf4(&sm.mq.zsh[1024+j4]);
          float4 zg = ldf4(&sm.mq.zsh[2048+j4]), zo = ldf4(&sm.mq.zsh[3072+j4]);
          float4 cp = ldf4(qcP + b*QHsz + j4);
          float4 cn, hn;
          cn.x = sigm(zf.x)*cp.x + sigm(zi.x)*tanhfast(zg.x); hn.x = sigm(zo.x)*tanhfast(cn.x);
          cn.y = sigm(zf.y)*cp.y + sigm(zi.y)*tanhfast(zg.y); hn.y = sigm(zo.y)*tanhfast(cn.y);
          cn.z = sigm(zf.z)*cp.z + sigm(zi.z)*tanhfast(zg.z); hn.z = sigm(zo.z)*tanhfast(cn.z);
          cn.w = sigm(zf.w)*cp.w + sigm(zi.w)*tanhfast(zg.w); hn.w = sigm(zo.w)*tanhfast(cn.w);
          *reinterpret_cast<float4*>(qcQ + b*QHsz + j4) = cn;
          *reinterpret_cast<float4*>(qh_state + b*QHsz + j4) = hn;
          sm.mq.qh2l[tid*2+0] = pk2(hn.x, hn.y);
          sm.mq.qh2l[tid*2+1] = pk2(hn.z, hn.w);
        }
        __syncthreads();
        {
          int r = tid >> 1, kh = tid & 1;
          const h2* wr = (const h2*)(h_wq + (size_t)r*QHsz + kh*512);
          const h2* xr = &sm.mq.qh2l[kh*256];
          float acc = 0.f;
          #pragma unroll 4
          for (int k=0;k<256;k+=8){
            F4H wA, wB, xA, xB;
            wA.f = ldf4((const float*)(wr + k));
            wB.f = ldf4((const float*)(wr + k + 4));
            xA.f = ldf4((const float*)(xr + k));
            xB.f = ldf4((const float*)(xr + k + 4));
            #pragma unroll
            for (int j=0;j<4;j++){
              acc = fdot2f(wA.h[j], xA.h[j], acc);
              acc = fdot2f(wB.h[j], xB.h[j], acc);
            }
          }
          acc += __shfl_xor(acc, 1, 64);
          if (kh == 0) pqws[b*ATTNsz + r] = acc;
        }
      }
    } else if (bid < 48){
      if (do_d){
        int db = bid - 16;
        int b = db & 15, half = db >> 4;
        int tm = t - 1;
        int lane = tid & 63, wv = tid >> 6;
        #pragma unroll
        for (int i=0;i<4;i++){
          int r4 = (tid + i*256)*4;
          float4 bi = ldf4(d_bih + r4), bh = ldf4(d_bhh + r4);
          float4 a = {bi.x+bh.x, bi.y+bh.y, bi.z+bh.z, bi.w+bh.w};
          #pragma unroll
          for (int c=0;c<10;c++){
            float4 p = ldf4(dpart + ((size_t)(c*16 + b))*4096 + r4);
            a.x += p.x; a.y += p.y; a.z += p.z; a.w += p.w;
          }
          *reinterpret_cast<float4*>(&sm.md.zsh[r4]) = a;
        }
        if (tid == 0){
          float m0=emaxP[b*4+0], m1=emaxP[b*4+1], m2=emaxP[b*4+2], m3=emaxP[b*4+3];
          float gm = fmaxf(fmaxf(m0,m1), fmaxf(m2,m3));
          float e0=__expf(m0-gm), e1=__expf(m1-gm), e2=__expf(m2-gm), e3=__expf(m3-gm);
          float gs = esumP[b*4+0]*e0 + esumP[b*4+1]*e1 + esumP[b*4+2]*e2 + esumP[b*4+3]*e3;
          float inv = 1.0f/gs;
          sm.md.scs[0]=e0*inv; sm.md.scs[1]=e1*inv; sm.md.scs[2]=e2*inv; sm.md.scs[3]=e3*inv;
        }
        __syncthreads();
        {
          int j4 = tid*4;
          float4 zi = ldf4(&sm.md.zsh[j4]), zf = ldf4(&sm.md.zsh[1024+j4]);
          float4 zg = ldf4(&sm.md.zsh[2048+j4]), zo = ldf4(&sm.md.zsh[3072+j4]);
          float4 cp = ldf4(dcP + b*DHsz + j4);
          float4 cn, hn;
          cn.x = sigm(zf.x)*cp.x + sigm(zi.x)*tanhfast(zg.x); hn.x = sigm(zo.x)*tanhfast(cn.x);
          cn.y = sigm(zf.y)*cp.y + sigm(zi.y)*tanhfast(zg.y); hn.y = sigm(zo.y)*tanhfast(cn.y);
          cn.z = sigm(zf.z)*cp.z + sigm(zi.z)*tanhfast(zg.z); hn.z = sigm(zo.z)*tanhfast(cn.z);
          cn.w = sigm(zf.w)*cp.w + sigm(zi.w)*tanhfast(zg.w); hn.w = sigm(zo.w)*tanhfast(cn.w);
          if (half == 0){
            *reinterpret_cast<float4*>(dcQ + b*DHsz + j4) = cn;
            *reinterpret_cast<float4*>(dh_state + b*DHsz + j4) = hn;
          }
          sm.md.feath[tid*2+0] = pk2(hn.x, hn.y);
          sm.md.feath[tid*2+1] = pk2(hn.z, hn.w);
        }
        __syncthreads();
        {
          float s0=sm.md.scs[0], s1=sm.md.scs[1], s2=sm.md.scs[2], s3=sm.md.scs[3];
          int i0 = tid*2;
          const float* cp = cpartP + (size_t)b*2048;
          float v0 = s0*cp[i0]   + s1*cp[512+i0]   + s2*cp[1024+i0]   + s3*cp[1536+i0];
          float v1 = s0*cp[i0+1] + s1*cp[512+i0+1] + s2*cp[1024+i0+1] + s3*cp[1536+i0+1];
          sm.md.feath[512 + tid] = pk2(v0, v1);
        }
        __syncthreads();
        int rbeg = half*40, rend = half ? 81 : 40;
        for (int r = rbeg + wv; r < rend; r += 4){
          const h2* wr = (r < 80) ? (const h2*)(h_proj + (size_t)r*1536) : (const h2*)h_gate;
          float acc = 0.0f;
          #pragma unroll
          for (int m=0;m<3;m++){
            int k4 = (lane + 64*m)*4;
            F4H w, x;
            w.f = ldf4((const float*)(wr + k4));
            x.f = ldf4((const float*)(&sm.md.feath[k4]));
            #pragma unroll
            for (int j=0;j<4;j++) acc = fdot2f(w.h[j], x.h[j], acc);
          }
          #pragma unroll
          for (int off=32; off>0; off>>=1) acc += __shfl_xor(acc, off, 64);
          if (lane == 0){
            if (r < 80) out_mel[((size_t)b*Tsz + tm)*NMELS + r] = acc + proj_b[r];
            else        out_stop[b*Tsz + tm] = sigm(acc + gate_b[0]);
          }
        }
      }
    }
    bt++; gridbar(cnt, bt*NB);

    // ======== Phase M2: energies + softmax stats + cpart (64 blocks) ========
    if (bid < 64 && do_q){
      int b = bid & 15, lc = bid >> 4;
      int l0 = lc*100;
      if (tid < 128) sm.m2.pqv[tid] = pqws[b*ATTNsz + tid];
      else sm.m2.vsh[tid-128] = vvec[tid-128];
      __syncthreads();
      {
        int ll = tid >> 1, ah = tid & 1;
        float e = 0.f;
        if (ll < 100){
          int l = l0 + ll;
          const h2* lp  = (const h2*)(loch + ((size_t)b*Lsz + l)*ATTNsz) + ah*32;
          const h2* pp2 = (const h2*)(pmh  + ((size_t)b*Lsz + l)*ATTNsz) + ah*32;
          const float* pqa = &sm.m2.pqv[ah*64];
          const float* va  = &sm.m2.vsh[ah*64];
          #pragma unroll 2
          for (int a2=0; a2<32; a2+=4){
            F4H l4, p4;
            l4.f = ldf4((const float*)(lp + a2));
            p4.f = ldf4((const float*)(pp2 + a2));
            #pragma unroll
            for (int j=0;j<4;j++){
              int a = (a2+j)*2;
              e += tanhfast(pqa[a]   + (float)l4.h[j].x + (float)p4.h[j].x) * va[a];
              e += tanhfast(pqa[a+1] + (float)l4.h[j].y + (float)p4.h[j].y) * va[a+1];
            }
          }
        }
        e += __shfl_xor(e, 1, 64);
        if (ll < 100 && ah == 0) sm.m2.esh[ll] = e;
      }
      __syncthreads();
      float lm = -1e30f;
      for (int i=tid; i<100; i+=256) lm = fmaxf(lm, sm.m2.esh[i]);
      sm.m2.red[tid] = lm; __syncthreads();
      for (int s=128; s>0; s>>=1){ if (tid<s) sm.m2.red[tid] = fmaxf(sm.m2.red[tid], sm.m2.red[tid+s]); __syncthreads(); }
      float mx = sm.m2.red[0]; __syncthreads();
      float ls = 0.f;
      for (int i=tid; i<100; i+=256){ float p = __expf(sm.m2.esh[i]-mx); sm.m2.pesh[i] = p; ls += p; }
      sm.m2.red[tid] = ls; __syncthreads();
      for (int s=128; s>0; s>>=1){ if (tid<s) sm.m2.red[tid] += sm.m2.red[tid+s]; __syncthreads(); }
      for (int i=tid; i<100; i+=256) ebufQ[b*Lsz + l0 + i] = sm.m2.esh[i];
      if (tid == 0){ emaxQ[b*4+lc] = mx; esumQ[b*4+lc] = sm.m2.red[0]; }
      __syncthreads();
      {
        int e4 = tid & 127, lh = tid >> 7;
        const float* mp = memory + ((size_t)b*Lsz + l0)*ENC + e4*4;
        float4 a = {0.f,0.f,0.f,0.f};
        for (int l = lh*50; l < lh*50+50; l++){
          float w = sm.m2.pesh[l];
          float4 m4 = ldf4(mp + (size_t)l*ENC);
          a.x += w*m4.x; a.y += w*m4.y; a.z += w*m4.z; a.w += w*m4.w;
        }
        if (lh == 1) sm.m2.psum[e4] = a;
        __syncthreads();
        if (lh == 0){
          float4 p = sm.m2.psum[e4];
          a.x += p.x; a.y += p.y; a.z += p.z; a.w += p.w;
          *reinterpret_cast<float4*>(cpartQ + ((size_t)b*4 + lc)*512 + e4*4) = a;
        }
      }
    }
    bt++; gridbar(cnt, bt*NB);
  }
}

extern "C" void kernel_launch(void* const* d_in, const int* in_sizes, int n_in,
                              void* d_out, int out_size, void* d_ws, size_t ws_size,
                              hipStream_t stream)
{
  const float* memory  = (const float*)d_in[0];
  const float* teacher = (const float*)d_in[2];
  const float* pre_w1  = (const float*)d_in[3];
  const float* pre_w2  = (const float*)d_in[4];
  const float* q_wih   = (const float*)d_in[5];
  const float* q_whh   = (const float*)d_in[6];
  const float* q_bih   = (const float*)d_in[7];
  const float* q_bhh   = (const float*)d_in[8];
  const float* d_wih   = (const float*)d_in[9];
  const float* d_whh   = (const float*)d_in[10];
  const float* d_bih   = (const float*)d_in[11];
  const float* d_bhh   = (const float*)d_in[12];
  const float* attn_wq   = (const float*)d_in[13];
  const float* attn_wm   = (const float*)d_in[14];
  const float* attn_conv = (const float*)d_in[15];
  const float* attn_wloc = (const float*)d_in[16];
  const float* attn_v    = (const float*)d_in[17];
  const float* proj_w  = (const float*)d_in[18];
  const float* proj_b  = (const float*)d_in[19];
  const float* gate_w  = (const float*)d_in[20];
  const float* gate_b  = (const float*)d_in[21];

  float* ws = (float*)d_ws;
  float* dec_ins  = ws;                 // 819200
  float* pmh_f    = dec_ins + 819200;   // 409600 floats (819200 hf)
  float* loch_f   = pmh_f + 409600;     // 409600
  float* qpart    = loch_f + 409600;    // 458752
  float* dpart    = qpart + 458752;     // 655360
  float* pqws     = dpart + 655360;     // 2048
  float* ebuf2    = pqws + 2048;        // 12800
  float* emax2    = ebuf2 + 12800;      // 128
  float* esum2    = emax2 + 128;        // 128
  float* cpart2   = esum2 + 128;        // 65536
  float* qh_state = cpart2 + 65536;     // 16384  <- zero from here
  float* dh_state = qh_state + 16384;   // 16384
  float* qc2      = dh_state + 16384;   // 32768
  float* dc2      = qc2 + 32768;        // 32768
  float* aws2     = dc2 + 32768;        // 12800
  int*   cnt      = (int*)(aws2 + 12800); // 64 ints -> zeroed
  float* fend     = aws2 + 12800 + 64;

  hf* pmh   = (hf*)pmh_f;
  hf* loch  = (hf*)loch_f;
  hf* h_qwih = (hf*)fend;               // 3145728 hf
  hf* h_qwhh = h_qwih + 3145728;        // 4194304
  hf* h_dwih = h_qwhh + 4194304;        // 6291456
  hf* h_dwhh = h_dwih + 6291456;        // 4194304
  hf* h_wq   = h_dwhh + 4194304;        // 131072
  hf* h_proj = h_wq + 131072;           // 122880
  hf* h_gate = h_proj + 122880;         // 1536

  float* out_mel   = (float*)d_out;
  float* out_align = out_mel + (size_t)Bsz*Tsz*NMELS;
  float* out_stop  = out_align + (size_t)Bsz*Tsz*Lsz;

  const int stateN = 16384+16384+32768+32768+12800+64;
  kzero<<<dim3((stateN+255)/256), dim3(256), 0, stream>>>(qh_state, stateN);
  kcvt<<<dim3(3145728/1024), dim3(256), 0, stream>>>(q_wih, h_qwih, 3145728);
  kcvt<<<dim3(4194304/1024), dim3(256), 0, stream>>>(q_whh, h_qwhh, 4194304);
  kcvt<<<dim3(6291456/1024), dim3(256), 0, stream>>>(d_wih, h_dwih, 6291456);
  kcvt<<<dim3(4194304/1024), dim3(256), 0, stream>>>(d_whh, h_dwhh, 4194304);
  kcvt<<<dim3(131072/1024), dim3(256), 0, stream>>>(attn_wq, h_wq, 131072);
  kcvt<<<dim3(122880/1024), dim3(256), 0, stream>>>(proj_w, h_proj, 122880);
  kcvt<<<dim3(2), dim3(256), 0, stream>>>(gate_w, h_gate, 1536);
  kprenet2<<<dim3(16*13), dim3(256), 0, stream>>>(teacher, pre_w1, pre_w2, dec_ins);
  kpm2h<<<dim3(400), dim3(256), 0, stream>>>(memory, attn_wm, pmh);

  kpers<<<dim3(NB), dim3(256), 0, stream>>>(
    dec_ins, pmh, loch, memory,
    qpart, dpart, pqws,
    ebuf2, emax2, esum2, cpart2,
    qh_state, dh_state, qc2, dc2, aws2,
    cnt,
    h_qwih, h_qwhh, h_dwih, h_dwhh,
    h_wq, h_proj, h_gate,
    q_bih, q_bhh, d_bih, d_bhh,
    attn_conv, attn_wloc, attn_v, proj_b, gate_b,
    out_mel, out_align, out_stop);
}